// Round 11
// baseline (643.610 us; speedup 1.0000x reference)
//
#include <hip/hip_runtime.h>

#define BB 32
#define NN 576
#define DD 1024
#define KK 128
#define HS_N 577

typedef float v2f __attribute__((ext_vector_type(2)));

// packed FMA: ACC = (fma(A.lo,B.lo,ACC.lo), fma(A.lo,B.hi,ACC.hi))  [broadcast A.lo]
#define PKFMA_LO(ACC, A, B)                                                    \
    asm("v_pk_fma_f32 %0, %1, %2, %0 op_sel:[0,0,0] op_sel_hi:[0,1,1]"         \
        : "+v"(ACC) : "v"(A), "v"(B))
// packed FMA: ACC = (fma(A.hi,B.lo,ACC.lo), fma(A.hi,B.hi,ACC.hi))  [broadcast A.hi]
#define PKFMA_HI(ACC, A, B)                                                    \
    asm("v_pk_fma_f32 %0, %1, %2, %0 op_sel:[1,0,0] op_sel_hi:[1,1,1]"         \
        : "+v"(ACC) : "v"(A), "v"(B))

struct V2x2 { v2f lo, hi; };

// ---------------- norm kernel: inv[b,n] = 1/||feats[b,n,:]|| ----------------
__global__ __launch_bounds__(256) void norm_kernel(const float* __restrict__ hs,
                                                   float* __restrict__ inv) {
    int row = blockIdx.x;              // b*NN + n
    int b = row / NN, n = row % NN;
    const float4* p = (const float4*)(hs + ((size_t)b * HS_N + n + 1) * DD);
    int t = threadIdx.x;
    float4 v = p[t];
    double s = (double)v.x * v.x + (double)v.y * v.y + (double)v.z * v.z + (double)v.w * v.w;
    for (int off = 32; off; off >>= 1) s += __shfl_xor(s, off);
    __shared__ double wsum[4];
    int lane = t & 63, w = t >> 6;
    if (lane == 0) wsum[w] = s;
    __syncthreads();
    if (t == 0) {
        double tot = wsum[0] + wsum[1] + wsum[2] + wsum[3];
        inv[row] = 1.0f / (float)sqrt(tot);
    }
}

// ---------------- sim GEMM (symmetric): 96x96 tiles, 21 upper-tri pairs -----
// v11: round-10 accounting put sim at ~230 us vs a 77 us FMA floor -- the
// 64x64 tile reads 32 LDS B per 16 FLOP and moves 737 MB of HBM panels.
// 96x96 tiles (576 = 6x96 EXACT, no guards): 6x6 outputs/thread -> 24 LDS B
// per 36 FLOP (2.7x), panels 528 MB (-28%), 672 blocks (8x84, XCD-chunked).
// LDS slot layout: row r -> slot (r/6)*12 + r%6, LDK=196 -> hot b128 reads
// land on 8 distinct bank-quads (~2-way, free per m136). Single LDS buffer +
// register prefetch (2 barriers/iter); 48 KB -> 3 blocks/CU. Math: same
// fused fma per element, k ascending 0..1023 -> sim BITWISE identical to
// v8/v9/v10 (validated absmax 0.0).
#define TS 96
#define NTT 6
#define NPAIR 21
#define KC2 32
#define LDK 196    // words per k-row: 16 groups * 12 + 4 pad
#define TLD2 100
__global__ __launch_bounds__(256) void sim_kernel(const float* __restrict__ hs,
                                                  const float* __restrict__ inv,
                                                  float* __restrict__ sim) {
    int id = blockIdx.x;               // 0..671
    int xcd = id & 7;
    int s = id >> 3;                   // 0..83
    int b = xcd + 8 * (s / NPAIR);
    int l = s % NPAIR;                 // 0..20 -> (ti,tj), ti<=tj
    int ti = 0;
    while (l >= NTT - ti) { l -= NTT - ti; ti++; }
    int tj = ti + l;
    int m0 = ti * TS, n0 = tj * TS;
    const float* feats = hs + ((size_t)b * HS_N + 1) * DD;
    __shared__ float smem[2 * KC2 * LDK];      // As | Bs ; tile overlays both
    float* As = smem;
    float* Bs = smem + KC2 * LDK;
    float* tile = smem;                        // 96*100 = 9600 <= 12544 floats
    int t = threadIdx.x;
    // staging map: float4 f = t + 256q (q 0..2): row r = f>>3, col4 = f&7
    int r0 = t >> 3, col4 = t & 7;             // r_q = r0 + 32q
    int sA[3]; float ivA[3], ivB[3];
    const float* pA[3]; const float* pB[3];
#pragma unroll
    for (int q = 0; q < 3; q++) {
        int r = r0 + 32 * q;
        int slot = (r / 6) * 12 + (r % 6);
        sA[q] = (col4 << 2) * LDK + slot;
        ivA[q] = inv[b * NN + m0 + r];
        ivB[q] = inv[b * NN + n0 + r];
        pA[q] = feats + (size_t)(m0 + r) * DD + (col4 << 2);
        pB[q] = feats + (size_t)(n0 + r) * DD + (col4 << 2);
    }
    int tx = t & 15, ty = t >> 4;
    v2f acc[6][3] = {};                        // acc[i][jp] = (c[i][2jp], c[i][2jp+1])
    float4 va[3], vb[3];
#pragma unroll
    for (int q = 0; q < 3; q++) { va[q] = *(const float4*)(pA[q]); vb[q] = *(const float4*)(pB[q]); }
    for (int k0 = 0; k0 < DD; k0 += KC2) {
        __syncthreads();   // previous compute (or nothing) done before overwrite
#pragma unroll
        for (int q = 0; q < 3; q++) {
            As[sA[q] + 0 * LDK] = va[q].x * ivA[q];
            As[sA[q] + 1 * LDK] = va[q].y * ivA[q];
            As[sA[q] + 2 * LDK] = va[q].z * ivA[q];
            As[sA[q] + 3 * LDK] = va[q].w * ivA[q];
            Bs[sA[q] + 0 * LDK] = vb[q].x * ivB[q];
            Bs[sA[q] + 1 * LDK] = vb[q].y * ivB[q];
            Bs[sA[q] + 2 * LDK] = vb[q].z * ivB[q];
            Bs[sA[q] + 3 * LDK] = vb[q].w * ivB[q];
        }
        __syncthreads();
        if (k0 + KC2 < DD) {   // global prefetch hides under compute
#pragma unroll
            for (int q = 0; q < 3; q++) {
                va[q] = *(const float4*)(pA[q] + k0 + KC2);
                vb[q] = *(const float4*)(pB[q] + k0 + KC2);
            }
        }
#pragma unroll
        for (int kk = 0; kk < KC2; kk++) {
            const float* Ar = &As[kk * LDK + tx * 12];
            const float* Br = &Bs[kk * LDK + ty * 12];
            float4 a4 = *(const float4*)Ar;  float2 a2 = *(const float2*)(Ar + 4);
            float4 b4 = *(const float4*)Br;  float2 b2 = *(const float2*)(Br + 4);
            V2x2 paq = __builtin_bit_cast(V2x2, a4);
            V2x2 pbq = __builtin_bit_cast(V2x2, b4);
            v2f pa[3] = {paq.lo, paq.hi, __builtin_bit_cast(v2f, a2)};
            v2f pb[3] = {pbq.lo, pbq.hi, __builtin_bit_cast(v2f, b2)};
#pragma unroll
            for (int ip = 0; ip < 3; ip++)
#pragma unroll
                for (int jp = 0; jp < 3; jp++) {
                    PKFMA_LO(acc[2 * ip][jp], pa[ip], pb[jp]);
                    PKFMA_HI(acc[2 * ip + 1][jp], pa[ip], pb[jp]);
                }
        }
    }
    // normal-orientation write (float2 granularity; n-offsets are 6-aligned)
#pragma unroll
    for (int i = 0; i < 6; i++) {
        float* dst = sim + ((size_t)b * NN + m0 + tx * 6 + i) * NN + n0 + ty * 6;
        *(float2*)(dst + 0) = make_float2(acc[i][0][0], acc[i][0][1]);
        *(float2*)(dst + 2) = make_float2(acc[i][1][0], acc[i][1][1]);
        *(float2*)(dst + 4) = make_float2(acc[i][2][0], acc[i][2][1]);
    }
    if (ti != tj) {
        // mirror via LDS bounce (tile overlays As/Bs, dead after k-loop)
        __syncthreads();
#pragma unroll
        for (int i = 0; i < 6; i++) {
            float* d = &tile[(tx * 6 + i) * TLD2 + ty * 6];
            *(float2*)(d + 0) = make_float2(acc[i][0][0], acc[i][0][1]);
            *(float2*)(d + 2) = make_float2(acc[i][1][0], acc[i][1][1]);
            *(float2*)(d + 4) = make_float2(acc[i][2][0], acc[i][2][1]);
        }
        __syncthreads();
#pragma unroll
        for (int i = 0; i < 6; i++) {
            int a = tx * 6 + i;                    // local n index (output row)
            float o0 = tile[(ty * 6 + 0) * TLD2 + a];
            float o1 = tile[(ty * 6 + 1) * TLD2 + a];
            float o2 = tile[(ty * 6 + 2) * TLD2 + a];
            float o3 = tile[(ty * 6 + 3) * TLD2 + a];
            float o4 = tile[(ty * 6 + 4) * TLD2 + a];
            float o5 = tile[(ty * 6 + 5) * TLD2 + a];
            float* dst = sim + ((size_t)b * NN + n0 + a) * NN + m0 + ty * 6;
            *(float2*)(dst + 0) = make_float2(o0, o1);
            *(float2*)(dst + 2) = make_float2(o2, o3);
            *(float2*)(dst + 4) = make_float2(o4, o5);
        }
    }
}

// -------- init gains on all CUs: g0[b,m] = sum_n max(sim[b,m,n],0) ----------
__global__ __launch_bounds__(256) void init_gain_kernel(const float* __restrict__ sim,
                                                        double* __restrict__ g0,
                                                        float* __restrict__ pad) {
    if (blockIdx.x == 0 && blockIdx.y == 0) {
        int tt = threadIdx.x;
        pad[tt] = 0.f; pad[tt + 256] = 0.f;
        if (tt < 64) pad[tt + 512] = 0.f;
    }
    int b = blockIdx.y;
    int m = (blockIdx.x << 2) + (threadIdx.x >> 6);
    int lane = threadIdx.x & 63;
    const float* row = sim + ((size_t)b * NN + m) * NN;
    double s = 0.0;
#pragma unroll
    for (int j = 0; j < 9; j++) s += (double)fmaxf(row[(j << 6) + lane], 0.f);
    for (int off = 32; off; off >>= 1) s += __shfl_xor(s, off);
    if (lane == 0) g0[b * NN + m] = s;
}

// ------- selection: 9 waves x 1 candidate, idx-free argmax ------------------
// v11 = v10 unchanged (validated 351 us, absmax 0.0): byte-offset chlist,
// chonw side-array, fmed3f identity, triple-buffered guarded prefetch,
// value-only fmax butterfly + ballot/ctz index recovery, spec 9-row tail.
#define LOAD_BUF8(X, N4, J)                                                    \
    {                                                                          \
        int jj8 = (J) << 3;                                                    \
        int4 oa = *(const int4*)&choff[jj8];                                   \
        int4 ob = *(const int4*)&choff[jj8 + 4];                               \
        X[0] = *(const float*)(Sc + (unsigned)(oa.x + t4));                    \
        X[1] = *(const float*)(Sc + (unsigned)(oa.y + t4));                    \
        X[2] = *(const float*)(Sc + (unsigned)(oa.z + t4));                    \
        X[3] = *(const float*)(Sc + (unsigned)(oa.w + t4));                    \
        X[4] = *(const float*)(Sc + (unsigned)(ob.x + t4));                    \
        X[5] = *(const float*)(Sc + (unsigned)(ob.y + t4));                    \
        X[6] = *(const float*)(Sc + (unsigned)(ob.z + t4));                    \
        X[7] = *(const float*)(Sc + (unsigned)(ob.w + t4));                    \
        int jh = (J) << 2;                                                     \
        N4[0] = chonw4[jh + 0];                                                \
        N4[1] = chonw4[jh + 1];                                                \
        N4[2] = chonw4[jh + 2];                                                \
        N4[3] = chonw4[jh + 3];                                                \
    }

#define COMP_BUF8(X, N4)                                                       \
    {                                                                          \
        _Pragma("unroll") for (int q = 0; q < 4; q++) {                        \
            float o0 = N4[q].x, w0 = N4[q].y;                                  \
            gg += (double)(o0 - __builtin_amdgcn_fmed3f(X[2 * q], o0, w0));    \
            float o1 = N4[q].z, w1 = N4[q].w;                                  \
            gg += (double)(o1 - __builtin_amdgcn_fmed3f(X[2 * q + 1], o1, w1));\
        }                                                                      \
    }

__global__ __launch_bounds__(576, 1) void select_kernel(const float* __restrict__ sim,
                                                        const double* __restrict__ g0,
                                                        const float* __restrict__ cls,
                                                        float* __restrict__ out_idx,
                                                        int* __restrict__ gsorted) {
    int b = blockIdx.x;
    const float* S = sim + (size_t)b * NN * NN;
    const char* Sc = (const char*)S;
    int t = threadIdx.x, lane = t & 63, w = t >> 6;   // w in 0..8
    const int t4 = t << 2;
    __shared__ float2 ovnw[NN];            // (old cmax, new cmax) per column
    __shared__ int    choff[NN + 8];       // byte offsets col*2304, chlist order
    __shared__ float4 chonw4[(NN + 8) / 2];// (o,nw) pairs, chlist order
    __shared__ unsigned long long chmask[9];
    __shared__ double rv[9];
    __shared__ int    ri[9];
    __shared__ float  selseq[KK];
    __shared__ int    wcnt[9];
    float2* chonw = (float2*)chonw4;

    double gg = g0[b * NN + t];
    double cl = (double)cls[b * NN + t];
    float mycmax = 0.f;
    bool sel = false;
    const int c0 = t;

    for (int k = 0; k < KK; k++) {
        // ---- phase 1: delta-update over step-(k-1) changed columns ----
        if (k > 0) {
            int pos = 0;
#pragma unroll
            for (int q = 0; q < 9; q++) {
                unsigned long long m = chmask[q];
                if ((m >> lane) & 1ull) {
                    int col = (q << 6) + lane;
                    int p = pos + __popcll(m & ((1ull << lane) - 1ull));
                    choff[p] = col * 2304;
                    chonw[p] = ovnw[col];
                }
                pos += __popcll(m);
            }
            int cc = pos;
            int padc = (8 - (cc & 7)) & 7;
            if (lane < padc) {                         // dummy col: d == 0 exactly
                choff[cc + lane] = NN * 2304;
                chonw[cc + lane] = make_float2(0.f, 0.f);
            }
            int nbat = (cc + padc) >> 3;               // >= 1 (winner's row always changes)

            float xA[8]; float4 nA[4];
            float xB[8]; float4 nB[4];
            float xC[8]; float4 nC[4];
            LOAD_BUF8(xA, nA, 0);
            if (nbat > 1) LOAD_BUF8(xB, nB, 1);
            for (int j = 0; j < nbat; ) {
                if (j + 2 < nbat) LOAD_BUF8(xC, nC, j + 2);
                __builtin_amdgcn_sched_barrier(0);
                COMP_BUF8(xA, nA);
                j++;
                if (j >= nbat) break;
                if (j + 2 < nbat) LOAD_BUF8(xA, nA, j + 2);
                __builtin_amdgcn_sched_barrier(0);
                COMP_BUF8(xB, nB);
                j++;
                if (j >= nbat) break;
                if (j + 2 < nbat) LOAD_BUF8(xB, nB, j + 2);
                __builtin_amdgcn_sched_barrier(0);
                COMP_BUF8(xC, nC);
                j++;
            }
        }
        // ---- argmax: value-only fmax butterfly + ballot index recovery ----
        double v = sel ? -1.0 : gg * cl;               // v in {-1} U [0, inf)
        double vr = v;
        for (int off = 32; off; off >>= 1)
            vr = fmax(vr, __shfl_xor(vr, off));        // all lanes -> wave max
        unsigned long long em = __ballot(v == vr);     // maximizer lanes (nonzero)
        if (lane == 0) {
            rv[w] = vr;
            ri[w] = (w << 6) + (int)__builtin_ctzll(em);   // smallest idx maximizer
        }
        __syncthreads();                           // A
        // ---- speculative tail loads overlap the 9-slot scan ----
        int risV[9];
#pragma unroll
        for (int q = 0; q < 9; q++) risV[q] = ri[q];
        float spec[9];
#pragma unroll
        for (int q = 0; q < 9; q++) spec[q] = S[(size_t)risV[q] * NN + t];
        double rvv[9];
#pragma unroll
        for (int q = 0; q < 9; q++) rvv[q] = rv[q];
        // tree-fmax over 9 (depth 4)
        double m01 = fmax(rvv[0], rvv[1]), m23 = fmax(rvv[2], rvv[3]);
        double m45 = fmax(rvv[4], rvv[5]), m67 = fmax(rvv[6], rvv[7]);
        double m03 = fmax(m01, m23), m47 = fmax(m45, m67);
        double bv = fmax(fmax(m03, m47), rvv[8]);
        // first q (ascending) with rvv[q] == bv -> smallest ri (ri asc in q)
        int mstar = risV[8]; float s0 = spec[8];
#pragma unroll
        for (int q = 8; q >= 0; q--) {
            bool hit = (rvv[q] == bv);
            mstar = hit ? risV[q] : mstar;
            s0 = hit ? spec[q] : s0;
        }
        // ---- tail: cmax update, ballot (s0 == S[mstar*NN+t] bitwise) ----
        float o0 = mycmax, n0 = fmaxf(o0, s0);
        bool h0 = n0 > o0;
        unsigned long long m0 = __ballot(h0);
        ovnw[c0] = make_float2(o0, n0); mycmax = n0;
        if (lane == 0) chmask[w] = m0;
        if (c0 == mstar) { sel = true; selseq[k] = (float)(mstar + 1); }
        __syncthreads();                           // B
    }

    // ---- epilogue: write selection order + sorted gather list ----
    if (t < KK) out_idx[b * KK + t] = selseq[t];
    unsigned long long mk = __ballot(sel);
    if (lane == 0) wcnt[w] = __popcll(mk);
    __syncthreads();
    int r = __popcll(mk & ((1ull << lane) - 1));
    int pre = 0;
#pragma unroll
    for (int q = 0; q < 9; q++) if (q < w) pre += wcnt[q];
    if (sel) gsorted[b * KK + pre + r] = c0 + 1;
}

// ---------------- gather: dominant_tokens[b,j,:] = hs[b, gsorted, :] --------
__global__ __launch_bounds__(256) void gather_kernel(const float* __restrict__ hs,
                                                     const int* __restrict__ gsorted,
                                                     float* __restrict__ out) {
    int blk = blockIdx.x;
    int b = blk >> 7, j = blk & 127;
    int row = gsorted[b * KK + j];
    const float4* src = (const float4*)(hs + ((size_t)b * HS_N + row) * DD);
    float4* dst = (float4*)(out + ((size_t)b * KK + j) * DD);
    dst[threadIdx.x] = src[threadIdx.x];
}

extern "C" void kernel_launch(void* const* d_in, const int* in_sizes, int n_in,
                              void* d_out, int out_size, void* d_ws, size_t ws_size,
                              hipStream_t stream) {
    const float* hs = (const float*)d_in[0];
    const float* cls = (const float*)d_in[1];
    // workspace layout: sim (42.5MB) | pad (576 floats, zeroed -- dummy-column
    // landing zone for b=31) | X: inv (norm->sim) / g0 (init->select, lifetimes
    // disjoint, g0 overlays inv) | gsorted (16KB)
    float* sim = (float*)d_ws;
    float* pad = sim + (size_t)BB * NN * NN;
    char* xregion = (char*)(pad + NN);
    float* inv = (float*)xregion;                  // BB*NN floats
    double* g0 = (double*)xregion;                 // BB*NN doubles (overlay)
    int* gsorted = (int*)(xregion + (size_t)BB * NN * sizeof(double));
    float* out_tokens = (float*)d_out;                       // [B,K,D] fp32
    float* out_idx = out_tokens + (size_t)BB * KK * DD;      // [B,K] indices as fp32

    norm_kernel<<<BB * NN, 256, 0, stream>>>(hs, inv);
    sim_kernel<<<21 * BB, 256, 0, stream>>>(hs, inv, sim);
    init_gain_kernel<<<dim3(NN / 4, BB), 256, 0, stream>>>(sim, g0, pad);
    select_kernel<<<BB, 576, 0, stream>>>(sim, g0, cls, out_idx, gsorted);
    gather_kernel<<<BB * KK, 256, 0, stream>>>(hs, gsorted, out_tokens);
}